// Round 1
// 529.655 us; speedup vs baseline: 1.2139x; 1.2139x over previous
//
#include <hip/hip_runtime.h>
#include <math.h>

#define NQ 16
#define NLAYERS 3
#define NSTATES 65536   // 2^16
#define BATCH 256

// Clamped global read: any harness/size mismatch becomes a wrong value,
// never an OOB fault.
__device__ __forceinline__ float rd(const float* __restrict__ p, int i, int n) {
    return p[i < n ? i : (n - 1)];
}

// ---------------------------------------------------------------------------
// static_for: compile-time loop. Indices arrive as IC<I> tags, so every
// state-array subscript is a literal constant in the IR the frontend emits.
// This is what lets SROA fully scalarize the 64-float state array.
// ---------------------------------------------------------------------------
template <int I> struct IC { static constexpr int v = I; };

template <int I, int N, typename F>
__device__ __forceinline__ void sfor_i(F& f) {
    if constexpr (I < N) {
        f(IC<I>{});
        sfor_i<I + 1, N>(f);
    }
}
template <int N, typename F>
__device__ __forceinline__ void sfor(F&& f) { sfor_i<0, N>(f); }

// ---------------------------------------------------------------------------
// One block (1024 threads) per batch element. State index = j*1024 + tid
// (j = register index 0..63).
//   bits 0..5   = lane bits     -> __shfl_xor
//   bits 6..9   = wave bits     -> LDS exchange (32 KiB, 8 chunks of 8 regs)
//   bits 10..15 = register bits -> in-register butterflies
// waves_per_eu(4,4): 128-VGPR budget for the 64-float register state.
//
// SPILL FIX (this round): the 64-wide shfl loops previously let the
// scheduler hoist dozens of ds_bpermute results -> ~64 extra live VGPRs on
// top of the 64-float state -> spill to scratch (rocprof: 2.57 GB HBM/dispatch,
// VGPR_Count=64). Chunk each shuffle gate into 8x{8 shfl+fma} groups fenced
// with sched_barrier(0) so at most 8 shuffle results are in flight.
//
// Output: dense float32 REAL parts (imag==0; all gate matrices real).
// ---------------------------------------------------------------------------
__global__ __launch_bounds__(1024)
__attribute__((amdgpu_waves_per_eu(4, 4)))
void qsim(const float* __restrict__ x,
          const float* __restrict__ rot,
          const float* __restrict__ ent,
          const float* __restrict__ W1,
          const float* __restrict__ b1,
          const float* __restrict__ W2,
          const float* __restrict__ b2,
          float* __restrict__ out,
          long long out_floats,
          int nx, int nrot, int nent, int nW1, int nb1, int nW2, int nb2) {
    const int tid = threadIdx.x;
    const int b   = blockIdx.x;

    __shared__ float  lds[8 * 1024];           // 32 KiB exchange buffer
    __shared__ float4 Mg[NLAYERS * NQ];        // 48 gate matrices
    __shared__ float  pg[NLAYERS * (NQ - 1)];  // 45 CNOT mix probs
    __shared__ float  hidS[64];
    __shared__ float  hqS[16];

    // ---- Phase A: MLP hidden layer (64 threads) + sigmoid probs ----
    if (tid < 64) {
        float s = rd(b1, tid, nb1);
        for (int k = 0; k < 100; k++)
            s = fmaf(rd(x, b * 100 + k, nx), rd(W1, k * 64 + tid, nW1), s);
        hidS[tid] = fmaxf(s, 0.f);
    } else if (tid >= 64 && tid < 64 + NLAYERS * (NQ - 1)) {
        int i = tid - 64;
        pg[i] = 1.f / (1.f + expf(-rd(ent, i, nent)));
    }
    __syncthreads();

    // ---- Phase B: output layer hq (16 threads) ----
    if (tid < 16) {
        float s = rd(b2, tid, nb2);
#pragma unroll
        for (int i = 0; i < 64; i++)
            s = fmaf(hidS[i], rd(W2, i * 16 + tid, nW2), s);
        hqS[tid] = tanhf(s);
    }
    __syncthreads();

    // ---- Phase C: gate matrices (48 threads) ----
    if (tid < NLAYERS * NQ) {
        int q = tid & 15;
        float hv = hqS[q];
        float a0 = 0.5f * rd(rot, tid * 3 + 0, nrot) * hv;
        float a1 = 0.5f * rd(rot, tid * 3 + 1, nrot) * hv;
        float a2 = 0.5f * rd(rot, tid * 3 + 2, nrot) * hv;
        float cx = cosf(a0), sx = sinf(a0);
        float cy = cosf(a1), sy = sinf(a1);
        float cz = cosf(a2), sz = sinf(a2);
        Mg[tid] = make_float4(cx * cy * cz, -(sx * sy * sz),
                              sx * sy * cz,  cx * cy * sz);
    }
    __syncthreads();

    // ---- statevector init: |0...0> ----
    float a[64];
    sfor<64>([&](auto J) { a[J.v] = 0.f; });
    if (tid == 0) a[0] = 1.f;

    for (int l = 0; l < NLAYERS; l++) {
        // ---------------- single-qubit gates ----------------
        // q = 0..5 : lane bits (shfl; q never indexes a[])
        // Chunked 8-wide + sched_barrier(0): cap in-flight bpermute results.
#pragma unroll
        for (int q = 0; q < 6; q++) {
            float4 m = Mg[l * NQ + q];
            int bit = (tid >> q) & 1;
            float cown  = bit ? m.w : m.x;
            float cpart = bit ? m.z : m.y;
            sfor<8>([&](auto C) {
                sfor<8>([&](auto K) {
                    constexpr int j = C.v * 8 + K.v;
                    float part = __shfl_xor(a[j], 1 << q);
                    a[j] = cown * a[j] + cpart * part;
                });
                __builtin_amdgcn_sched_barrier(0);
            });
        }
        // q = 6..9 : wave bits (LDS exchange, 8 chunks x 8 regs)
#pragma unroll
        for (int q = 6; q < 10; q++) {
            float4 m = Mg[l * NQ + q];
            int bit = (tid >> q) & 1;
            float cown  = bit ? m.w : m.x;
            float cpart = bit ? m.z : m.y;
            int partner = tid ^ (1 << q);
            sfor<8>([&](auto C) {
                __syncthreads();
                sfor<8>([&](auto K) {
                    lds[K.v * 1024 + tid] = a[C.v * 8 + K.v];
                });
                __syncthreads();
                sfor<8>([&](auto K) {
                    constexpr int idx = C.v * 8 + K.v;
                    float part = lds[K.v * 1024 + partner];
                    a[idx] = cown * a[idx] + cpart * part;
                });
            });
        }
        // q = 10..15 : register bits (in-register butterfly)
        sfor<6>([&](auto QQ) {
            float4 m = Mg[l * NQ + 10 + QQ.v];
            sfor<64>([&](auto J) {
                constexpr int h = 1 << QQ.v;
                if constexpr (!(J.v & h)) {
                    constexpr int j1 = J.v | h;
                    float a0 = a[J.v], a1 = a[j1];
                    a[J.v] = m.x * a0 + m.y * a1;
                    a[j1]  = m.z * a0 + m.w * a1;
                }
            });
        });

        // ---------------- noisy CNOTs: ctrl=q, tgt=q+1 ----------------
        // q = 0..4 : ctrl + tgt both lane bits (shfl on tgt), chunked + fenced
#pragma unroll
        for (int q = 0; q < 5; q++) {
            float p = pg[l * (NQ - 1) + q];
            int ctrl = (tid >> q) & 1;
            float pc = ctrl ? p : 0.f;
            float qc = ctrl ? (1.f - p) : 1.f;
            sfor<8>([&](auto C) {
                sfor<8>([&](auto K) {
                    constexpr int j = C.v * 8 + K.v;
                    float f = __shfl_xor(a[j], 1 << (q + 1));
                    a[j] = qc * a[j] + pc * f;
                });
                __builtin_amdgcn_sched_barrier(0);
            });
        }
        // q = 5..8 : tgt = 6..9 wave bits (LDS exchange)
#pragma unroll
        for (int q = 5; q < 9; q++) {
            float p = pg[l * (NQ - 1) + q];
            int ctrl = (tid >> q) & 1;
            float pc = ctrl ? p : 0.f;
            float qc = ctrl ? (1.f - p) : 1.f;
            int partner = tid ^ (1 << (q + 1));
            sfor<8>([&](auto C) {
                __syncthreads();
                sfor<8>([&](auto K) {
                    lds[K.v * 1024 + tid] = a[C.v * 8 + K.v];
                });
                __syncthreads();
                sfor<8>([&](auto K) {
                    constexpr int idx = C.v * 8 + K.v;
                    float f = lds[K.v * 1024 + partner];
                    a[idx] = qc * a[idx] + pc * f;
                });
            });
        }
        // q = 9 : ctrl wave bit 9, tgt register bit 0
        {
            float p = pg[l * (NQ - 1) + 9];
            int ctrl = (tid >> 9) & 1;
            float pc = ctrl ? p : 0.f;
            float qc = ctrl ? (1.f - p) : 1.f;
            sfor<32>([&](auto T) {
                constexpr int j = 2 * T.v;
                float a0 = a[j], a1 = a[j + 1];
                a[j]     = qc * a0 + pc * a1;
                a[j + 1] = qc * a1 + pc * a0;
            });
        }
        // q = 10..14 : ctrl and tgt both register bits
        sfor<5>([&](auto QQ) {
            float p = pg[l * (NQ - 1) + 10 + QQ.v];
            float onem = 1.f - p;
            sfor<64>([&](auto J) {
                constexpr int cmask = 1 << QQ.v;
                constexpr int tmask = 2 << QQ.v;
                if constexpr ((J.v & cmask) && !(J.v & tmask)) {
                    constexpr int j1 = J.v | tmask;
                    float a0 = a[J.v], a1 = a[j1];
                    a[J.v] = onem * a0 + p * a1;
                    a[j1]  = onem * a1 + p * a0;
                }
            });
        });
    }

    // ---------------- output: dense float32 real parts ----------------
    long long base = (long long)b * NSTATES;
    sfor<64>([&](auto J) {
        long long fi = base + (long long)(J.v * 1024) + tid;
        if (fi < out_floats) out[fi] = a[J.v];
    });
}

extern "C" void kernel_launch(void* const* d_in, const int* in_sizes, int n_in,
                              void* d_out, int out_size, void* d_ws, size_t ws_size,
                              hipStream_t stream) {
    const float* x   = (const float*)d_in[0];
    const float* rot = (const float*)d_in[1];
    const float* ent = (const float*)d_in[2];
    const float* W1  = (const float*)d_in[3];
    const float* b1  = (const float*)d_in[4];
    const float* W2  = (const float*)d_in[5];
    const float* b2  = (const float*)d_in[6];

    qsim<<<BATCH, 1024, 0, stream>>>(x, rot, ent, W1, b1, W2, b2,
                                     (float*)d_out, (long long)out_size,
                                     in_sizes[0], in_sizes[1], in_sizes[2],
                                     in_sizes[3], in_sizes[4], in_sizes[5],
                                     in_sizes[6]);
}

// Round 2
// 501.437 us; speedup vs baseline: 1.2822x; 1.0563x over previous
//
#include <hip/hip_runtime.h>
#include <math.h>

#define NQ 16
#define NLAYERS 3
#define NSTATES 65536   // 2^16
#define BATCH 256

// Clamped global read: any harness/size mismatch becomes a wrong value,
// never an OOB fault.
__device__ __forceinline__ float rd(const float* __restrict__ p, int i, int n) {
    return p[i < n ? i : (n - 1)];
}

// ---------------------------------------------------------------------------
// static_for: compile-time loop. Indices arrive as IC<I> tags, so every
// state-array subscript is a literal constant in the IR the frontend emits.
// This is what lets SROA fully scalarize the 64-float state array.
// ---------------------------------------------------------------------------
template <int I> struct IC { static constexpr int v = I; };

template <int I, int N, typename F>
__device__ __forceinline__ void sfor_i(F& f) {
    if constexpr (I < N) {
        f(IC<I>{});
        sfor_i<I + 1, N>(f);
    }
}
template <int N, typename F>
__device__ __forceinline__ void sfor(F&& f) { sfor_i<0, N>(f); }

// ---------------------------------------------------------------------------
// One block (1024 threads) per batch element. State index = j*1024 + tid
// (j = register index 0..63).
//   bits 0..5   = lane bits     -> __shfl_xor
//   bits 6..9   = wave bits     -> LDS exchange (8 chunks of 8 regs)
//   bits 10..15 = register bits -> in-register butterflies
//
// VGPR-BUDGET FIX (this round): rocprof showed VGPR_Count=64 — the backend
// targeted 8 waves/EU (LDS-derived occupancy at 34 KiB = 2 blocks/CU), so the
// 64-float state could never fit and ~1.8 GB/dispatch of scratch spill traffic
// dominated. Two redundant mechanisms force a 4-waves/EU target (128-VGPR
// budget):
//   1. amdgpu_flat_work_group_size + amdgpu_waves_per_eu(4,4) as a single
//      clang attribute set (no __launch_bounds__ interference).
//   2. LDS padded to 96 KiB so LDS-derived occupancy is 1 block/CU = 4
//      waves/EU even if the attribute is dropped. Free: grid is 256 blocks on
//      256 CUs, so only 1 block/CU ever runs anyway.
//
// Output: dense float32 REAL parts (imag==0; all gate matrices real).
// ---------------------------------------------------------------------------
__global__
__attribute__((amdgpu_flat_work_group_size(1024, 1024), amdgpu_waves_per_eu(4, 4)))
void qsim(const float* __restrict__ x,
          const float* __restrict__ rot,
          const float* __restrict__ ent,
          const float* __restrict__ W1,
          const float* __restrict__ b1,
          const float* __restrict__ W2,
          const float* __restrict__ b2,
          float* __restrict__ out,
          long long out_floats,
          int nx, int nrot, int nent, int nW1, int nb1, int nW2, int nb2) {
    const int tid = threadIdx.x;
    const int b   = blockIdx.x;

    // 96 KiB: first 8*1024 floats are the live exchange buffer; the rest is
    // occupancy ballast (see header comment). Referenced as one array so the
    // compiler cannot discard the padding.
    __shared__ float  lds[24 * 1024];
    __shared__ float4 Mg[NLAYERS * NQ];        // 48 gate matrices
    __shared__ float  pg[NLAYERS * (NQ - 1)];  // 45 CNOT mix probs
    __shared__ float  hidS[64];
    __shared__ float  hqS[16];

    // ---- Phase A: MLP hidden layer (64 threads) + sigmoid probs ----
    if (tid < 64) {
        float s = rd(b1, tid, nb1);
        for (int k = 0; k < 100; k++)
            s = fmaf(rd(x, b * 100 + k, nx), rd(W1, k * 64 + tid, nW1), s);
        hidS[tid] = fmaxf(s, 0.f);
    } else if (tid >= 64 && tid < 64 + NLAYERS * (NQ - 1)) {
        int i = tid - 64;
        pg[i] = 1.f / (1.f + expf(-rd(ent, i, nent)));
    }
    __syncthreads();

    // ---- Phase B: output layer hq (16 threads) ----
    if (tid < 16) {
        float s = rd(b2, tid, nb2);
#pragma unroll
        for (int i = 0; i < 64; i++)
            s = fmaf(hidS[i], rd(W2, i * 16 + tid, nW2), s);
        hqS[tid] = tanhf(s);
    }
    __syncthreads();

    // ---- Phase C: gate matrices (48 threads) ----
    if (tid < NLAYERS * NQ) {
        int q = tid & 15;
        float hv = hqS[q];
        float a0 = 0.5f * rd(rot, tid * 3 + 0, nrot) * hv;
        float a1 = 0.5f * rd(rot, tid * 3 + 1, nrot) * hv;
        float a2 = 0.5f * rd(rot, tid * 3 + 2, nrot) * hv;
        float cx = cosf(a0), sx = sinf(a0);
        float cy = cosf(a1), sy = sinf(a1);
        float cz = cosf(a2), sz = sinf(a2);
        Mg[tid] = make_float4(cx * cy * cz, -(sx * sy * sz),
                              sx * sy * cz,  cx * cy * sz);
    }
    __syncthreads();

    // ---- statevector init: |0...0> ----
    float a[64];
    sfor<64>([&](auto J) { a[J.v] = 0.f; });
    if (tid == 0) a[0] = 1.f;

    for (int l = 0; l < NLAYERS; l++) {
        // ---------------- single-qubit gates ----------------
        // q = 0..5 : lane bits (shfl; q never indexes a[])
        // Chunked 8-wide + sched_barrier(0): cap in-flight bpermute results.
#pragma unroll
        for (int q = 0; q < 6; q++) {
            float4 m = Mg[l * NQ + q];
            int bit = (tid >> q) & 1;
            float cown  = bit ? m.w : m.x;
            float cpart = bit ? m.z : m.y;
            sfor<8>([&](auto C) {
                sfor<8>([&](auto K) {
                    constexpr int j = C.v * 8 + K.v;
                    float part = __shfl_xor(a[j], 1 << q);
                    a[j] = cown * a[j] + cpart * part;
                });
                __builtin_amdgcn_sched_barrier(0);
            });
        }
        // q = 6..9 : wave bits (LDS exchange, 8 chunks x 8 regs)
#pragma unroll
        for (int q = 6; q < 10; q++) {
            float4 m = Mg[l * NQ + q];
            int bit = (tid >> q) & 1;
            float cown  = bit ? m.w : m.x;
            float cpart = bit ? m.z : m.y;
            int partner = tid ^ (1 << q);
            sfor<8>([&](auto C) {
                __syncthreads();
                sfor<8>([&](auto K) {
                    lds[K.v * 1024 + tid] = a[C.v * 8 + K.v];
                });
                __syncthreads();
                sfor<8>([&](auto K) {
                    constexpr int idx = C.v * 8 + K.v;
                    float part = lds[K.v * 1024 + partner];
                    a[idx] = cown * a[idx] + cpart * part;
                });
            });
        }
        // q = 10..15 : register bits (in-register butterfly)
        sfor<6>([&](auto QQ) {
            float4 m = Mg[l * NQ + 10 + QQ.v];
            sfor<64>([&](auto J) {
                constexpr int h = 1 << QQ.v;
                if constexpr (!(J.v & h)) {
                    constexpr int j1 = J.v | h;
                    float a0 = a[J.v], a1 = a[j1];
                    a[J.v] = m.x * a0 + m.y * a1;
                    a[j1]  = m.z * a0 + m.w * a1;
                }
            });
        });

        // ---------------- noisy CNOTs: ctrl=q, tgt=q+1 ----------------
        // q = 0..4 : ctrl + tgt both lane bits (shfl on tgt), chunked + fenced
#pragma unroll
        for (int q = 0; q < 5; q++) {
            float p = pg[l * (NQ - 1) + q];
            int ctrl = (tid >> q) & 1;
            float pc = ctrl ? p : 0.f;
            float qc = ctrl ? (1.f - p) : 1.f;
            sfor<8>([&](auto C) {
                sfor<8>([&](auto K) {
                    constexpr int j = C.v * 8 + K.v;
                    float f = __shfl_xor(a[j], 1 << (q + 1));
                    a[j] = qc * a[j] + pc * f;
                });
                __builtin_amdgcn_sched_barrier(0);
            });
        }
        // q = 5..8 : tgt = 6..9 wave bits (LDS exchange)
#pragma unroll
        for (int q = 5; q < 9; q++) {
            float p = pg[l * (NQ - 1) + q];
            int ctrl = (tid >> q) & 1;
            float pc = ctrl ? p : 0.f;
            float qc = ctrl ? (1.f - p) : 1.f;
            int partner = tid ^ (1 << (q + 1));
            sfor<8>([&](auto C) {
                __syncthreads();
                sfor<8>([&](auto K) {
                    lds[K.v * 1024 + tid] = a[C.v * 8 + K.v];
                });
                __syncthreads();
                sfor<8>([&](auto K) {
                    constexpr int idx = C.v * 8 + K.v;
                    float f = lds[K.v * 1024 + partner];
                    a[idx] = qc * a[idx] + pc * f;
                });
            });
        }
        // q = 9 : ctrl wave bit 9, tgt register bit 0
        {
            float p = pg[l * (NQ - 1) + 9];
            int ctrl = (tid >> 9) & 1;
            float pc = ctrl ? p : 0.f;
            float qc = ctrl ? (1.f - p) : 1.f;
            sfor<32>([&](auto T) {
                constexpr int j = 2 * T.v;
                float a0 = a[j], a1 = a[j + 1];
                a[j]     = qc * a0 + pc * a1;
                a[j + 1] = qc * a1 + pc * a0;
            });
        }
        // q = 10..14 : ctrl and tgt both register bits
        sfor<5>([&](auto QQ) {
            float p = pg[l * (NQ - 1) + 10 + QQ.v];
            float onem = 1.f - p;
            sfor<64>([&](auto J) {
                constexpr int cmask = 1 << QQ.v;
                constexpr int tmask = 2 << QQ.v;
                if constexpr ((J.v & cmask) && !(J.v & tmask)) {
                    constexpr int j1 = J.v | tmask;
                    float a0 = a[J.v], a1 = a[j1];
                    a[J.v] = onem * a0 + p * a1;
                    a[j1]  = onem * a1 + p * a0;
                }
            });
        });
    }

    // ---------------- output: dense float32 real parts ----------------
    long long base = (long long)b * NSTATES;
    sfor<64>([&](auto J) {
        long long fi = base + (long long)(J.v * 1024) + tid;
        if (fi < out_floats) out[fi] = a[J.v];
    });
}

extern "C" void kernel_launch(void* const* d_in, const int* in_sizes, int n_in,
                              void* d_out, int out_size, void* d_ws, size_t ws_size,
                              hipStream_t stream) {
    const float* x   = (const float*)d_in[0];
    const float* rot = (const float*)d_in[1];
    const float* ent = (const float*)d_in[2];
    const float* W1  = (const float*)d_in[3];
    const float* b1  = (const float*)d_in[4];
    const float* W2  = (const float*)d_in[5];
    const float* b2  = (const float*)d_in[6];

    qsim<<<BATCH, 1024, 0, stream>>>(x, rot, ent, W1, b1, W2, b2,
                                     (float*)d_out, (long long)out_size,
                                     in_sizes[0], in_sizes[1], in_sizes[2],
                                     in_sizes[3], in_sizes[4], in_sizes[5],
                                     in_sizes[6]);
}

// Round 3
// 428.751 us; speedup vs baseline: 1.4996x; 1.1695x over previous
//
#include <hip/hip_runtime.h>
#include <math.h>

#define NQ 16
#define NLAYERS 3
#define NSTATES 65536   // 2^16
#define BATCH 256

// Clamped global read: any harness/size mismatch becomes a wrong value,
// never an OOB fault.
__device__ __forceinline__ float rd(const float* __restrict__ p, int i, int n) {
    return p[i < n ? i : (n - 1)];
}

// ---------------------------------------------------------------------------
// static_for: compile-time loop. Indices arrive as IC<I> tags, so every
// state subscript is a literal constant.
// ---------------------------------------------------------------------------
template <int I> struct IC { static constexpr int v = I; };

template <int I, int N, typename F>
__device__ __forceinline__ void sfor_i(F& f) {
    if constexpr (I < N) {
        f(IC<I>{});
        sfor_i<I + 1, N>(f);
    }
}
template <int N, typename F>
__device__ __forceinline__ void sfor(F&& f) { sfor_i<0, N>(f); }

// ---------------------------------------------------------------------------
// State storage: FOUR named f32x16 ext_vectors (64 floats), never an array.
// Constant-index extract/insertelement is pure SSA — there is no 64-slice
// alloca for SROA to fumble (R3 fix for hypothesis "SROA never promoted
// float a[64]"; rocprof R0-R2: VGPR_Count stuck at 64 with ~1.7 GB/dispatch
// scratch traffic).
// ---------------------------------------------------------------------------
typedef float f32x16 __attribute__((ext_vector_type(16)));

template <int J>
__device__ __forceinline__ float getv(const f32x16& s0, const f32x16& s1,
                                      const f32x16& s2, const f32x16& s3) {
    if constexpr (J < 16)      return s0[J];
    else if constexpr (J < 32) return s1[J - 16];
    else if constexpr (J < 48) return s2[J - 32];
    else                       return s3[J - 48];
}
template <int J>
__device__ __forceinline__ void setv(f32x16& s0, f32x16& s1,
                                     f32x16& s2, f32x16& s3, float x) {
    if constexpr (J < 16)      s0[J] = x;
    else if constexpr (J < 32) s1[J - 16] = x;
    else if constexpr (J < 48) s2[J - 32] = x;
    else                       s3[J - 48] = x;
}

// ---------------------------------------------------------------------------
// One block (1024 threads) per batch element. State index = j*1024 + tid
// (j = vector-element index 0..63).
//   bits 0..5   = lane bits     -> __shfl_xor
//   bits 6..9   = wave bits     -> LDS exchange (8 chunks of 8 elems)
//   bits 10..15 = register bits -> in-register butterflies
//
// VGPR budget (R3 fix for hypothesis "budget pinned at 64"): occupancy-based
// routes (launch_bounds, waves_per_eu+LDS) both failed to move the budget off
// 64. amdgpu_num_vgpr(128) sets the cap DIRECTLY. Grid is 256 blocks on 256
// CUs -> 1 block/CU regardless, so 128 VGPRs costs nothing.
//
// Output: dense float32 REAL parts (imag==0; all gate matrices real).
// ---------------------------------------------------------------------------
__global__
__attribute__((amdgpu_flat_work_group_size(1024, 1024),
               amdgpu_waves_per_eu(4, 4),
               amdgpu_num_vgpr(128)))
void qsim(const float* __restrict__ x,
          const float* __restrict__ rot,
          const float* __restrict__ ent,
          const float* __restrict__ W1,
          const float* __restrict__ b1,
          const float* __restrict__ W2,
          const float* __restrict__ b2,
          float* __restrict__ out,
          long long out_floats,
          int nx, int nrot, int nent, int nW1, int nb1, int nW2, int nb2) {
    const int tid = threadIdx.x;
    const int b   = blockIdx.x;

    // 96 KiB: first 8*1024 floats are the live exchange buffer; the rest is
    // occupancy ballast pinning 1 block/CU (free: grid = 1 block/CU anyway).
    __shared__ float  lds[24 * 1024];
    __shared__ float4 Mg[NLAYERS * NQ];        // 48 gate matrices
    __shared__ float  pg[NLAYERS * (NQ - 1)];  // 45 CNOT mix probs
    __shared__ float  hidS[64];
    __shared__ float  hqS[16];

    // ---- Phase A: MLP hidden layer (64 threads) + sigmoid probs ----
    if (tid < 64) {
        float s = rd(b1, tid, nb1);
        for (int k = 0; k < 100; k++)
            s = fmaf(rd(x, b * 100 + k, nx), rd(W1, k * 64 + tid, nW1), s);
        hidS[tid] = fmaxf(s, 0.f);
    } else if (tid >= 64 && tid < 64 + NLAYERS * (NQ - 1)) {
        int i = tid - 64;
        pg[i] = 1.f / (1.f + expf(-rd(ent, i, nent)));
    }
    __syncthreads();

    // ---- Phase B: output layer hq (16 threads) ----
    if (tid < 16) {
        float s = rd(b2, tid, nb2);
#pragma unroll
        for (int i = 0; i < 64; i++)
            s = fmaf(hidS[i], rd(W2, i * 16 + tid, nW2), s);
        hqS[tid] = tanhf(s);
    }
    __syncthreads();

    // ---- Phase C: gate matrices (48 threads) ----
    if (tid < NLAYERS * NQ) {
        int q = tid & 15;
        float hv = hqS[q];
        float a0 = 0.5f * rd(rot, tid * 3 + 0, nrot) * hv;
        float a1 = 0.5f * rd(rot, tid * 3 + 1, nrot) * hv;
        float a2 = 0.5f * rd(rot, tid * 3 + 2, nrot) * hv;
        float cx = cosf(a0), sx = sinf(a0);
        float cy = cosf(a1), sy = sinf(a1);
        float cz = cosf(a2), sz = sinf(a2);
        Mg[tid] = make_float4(cx * cy * cz, -(sx * sy * sz),
                              sx * sy * cz,  cx * cy * sz);
    }
    __syncthreads();

    // ---- statevector init: |0...0> ----
    f32x16 s0 = (f32x16)0.f, s1 = (f32x16)0.f,
           s2 = (f32x16)0.f, s3 = (f32x16)0.f;
    if (tid == 0) s0[0] = 1.f;

#define AGET(J)    getv<(J)>(s0, s1, s2, s3)
#define ASET(J, X) setv<(J)>(s0, s1, s2, s3, (X))

    for (int l = 0; l < NLAYERS; l++) {
        // ---------------- single-qubit gates ----------------
        // q = 0..5 : lane bits (shfl). Chunked 8-wide + sched_barrier(0):
        // cap in-flight bpermute results.
#pragma unroll
        for (int q = 0; q < 6; q++) {
            float4 m = Mg[l * NQ + q];
            int bit = (tid >> q) & 1;
            float cown  = bit ? m.w : m.x;
            float cpart = bit ? m.z : m.y;
            sfor<8>([&](auto C) {
                sfor<8>([&](auto K) {
                    constexpr int j = C.v * 8 + K.v;
                    float part = __shfl_xor(AGET(j), 1 << q);
                    ASET(j, cown * AGET(j) + cpart * part);
                });
                __builtin_amdgcn_sched_barrier(0);
            });
        }
        // q = 6..9 : wave bits (LDS exchange, 8 chunks x 8 elems)
#pragma unroll
        for (int q = 6; q < 10; q++) {
            float4 m = Mg[l * NQ + q];
            int bit = (tid >> q) & 1;
            float cown  = bit ? m.w : m.x;
            float cpart = bit ? m.z : m.y;
            int partner = tid ^ (1 << q);
            sfor<8>([&](auto C) {
                __syncthreads();
                sfor<8>([&](auto K) {
                    lds[K.v * 1024 + tid] = AGET(C.v * 8 + K.v);
                });
                __syncthreads();
                sfor<8>([&](auto K) {
                    constexpr int idx = C.v * 8 + K.v;
                    float part = lds[K.v * 1024 + partner];
                    ASET(idx, cown * AGET(idx) + cpart * part);
                });
            });
        }
        // q = 10..15 : register bits (in-register butterfly)
        sfor<6>([&](auto QQ) {
            float4 m = Mg[l * NQ + 10 + QQ.v];
            sfor<64>([&](auto J) {
                constexpr int h = 1 << QQ.v;
                if constexpr (!(J.v & h)) {
                    constexpr int j1 = J.v | h;
                    float a0 = AGET(J.v), a1 = AGET(j1);
                    ASET(J.v, m.x * a0 + m.y * a1);
                    ASET(j1,  m.z * a0 + m.w * a1);
                }
            });
        });

        // ---------------- noisy CNOTs: ctrl=q, tgt=q+1 ----------------
        // q = 0..4 : ctrl + tgt both lane bits (shfl on tgt), chunked+fenced
#pragma unroll
        for (int q = 0; q < 5; q++) {
            float p = pg[l * (NQ - 1) + q];
            int ctrl = (tid >> q) & 1;
            float pc = ctrl ? p : 0.f;
            float qc = ctrl ? (1.f - p) : 1.f;
            sfor<8>([&](auto C) {
                sfor<8>([&](auto K) {
                    constexpr int j = C.v * 8 + K.v;
                    float f = __shfl_xor(AGET(j), 1 << (q + 1));
                    ASET(j, qc * AGET(j) + pc * f);
                });
                __builtin_amdgcn_sched_barrier(0);
            });
        }
        // q = 5..8 : tgt = 6..9 wave bits (LDS exchange)
#pragma unroll
        for (int q = 5; q < 9; q++) {
            float p = pg[l * (NQ - 1) + q];
            int ctrl = (tid >> q) & 1;
            float pc = ctrl ? p : 0.f;
            float qc = ctrl ? (1.f - p) : 1.f;
            int partner = tid ^ (1 << (q + 1));
            sfor<8>([&](auto C) {
                __syncthreads();
                sfor<8>([&](auto K) {
                    lds[K.v * 1024 + tid] = AGET(C.v * 8 + K.v);
                });
                __syncthreads();
                sfor<8>([&](auto K) {
                    constexpr int idx = C.v * 8 + K.v;
                    float f = lds[K.v * 1024 + partner];
                    ASET(idx, qc * AGET(idx) + pc * f);
                });
            });
        }
        // q = 9 : ctrl wave bit 9, tgt register bit 0
        {
            float p = pg[l * (NQ - 1) + 9];
            int ctrl = (tid >> 9) & 1;
            float pc = ctrl ? p : 0.f;
            float qc = ctrl ? (1.f - p) : 1.f;
            sfor<32>([&](auto T) {
                constexpr int j = 2 * T.v;
                float a0 = AGET(j), a1 = AGET(j + 1);
                ASET(j,     qc * a0 + pc * a1);
                ASET(j + 1, qc * a1 + pc * a0);
            });
        }
        // q = 10..14 : ctrl and tgt both register bits
        sfor<5>([&](auto QQ) {
            float p = pg[l * (NQ - 1) + 10 + QQ.v];
            float onem = 1.f - p;
            sfor<64>([&](auto J) {
                constexpr int cmask = 1 << QQ.v;
                constexpr int tmask = 2 << QQ.v;
                if constexpr ((J.v & cmask) && !(J.v & tmask)) {
                    constexpr int j1 = J.v | tmask;
                    float a0 = AGET(J.v), a1 = AGET(j1);
                    ASET(J.v, onem * a0 + p * a1);
                    ASET(j1,  onem * a1 + p * a0);
                }
            });
        });
    }

    // ---------------- output: dense float32 real parts ----------------
    long long base = (long long)b * NSTATES;
    sfor<64>([&](auto J) {
        long long fi = base + (long long)(J.v * 1024) + tid;
        if (fi < out_floats) out[fi] = AGET(J.v);
    });
#undef AGET
#undef ASET
}

extern "C" void kernel_launch(void* const* d_in, const int* in_sizes, int n_in,
                              void* d_out, int out_size, void* d_ws, size_t ws_size,
                              hipStream_t stream) {
    const float* x   = (const float*)d_in[0];
    const float* rot = (const float*)d_in[1];
    const float* ent = (const float*)d_in[2];
    const float* W1  = (const float*)d_in[3];
    const float* b1  = (const float*)d_in[4];
    const float* W2  = (const float*)d_in[5];
    const float* b2  = (const float*)d_in[6];

    qsim<<<BATCH, 1024, 0, stream>>>(x, rot, ent, W1, b1, W2, b2,
                                     (float*)d_out, (long long)out_size,
                                     in_sizes[0], in_sizes[1], in_sizes[2],
                                     in_sizes[3], in_sizes[4], in_sizes[5],
                                     in_sizes[6]);
}

// Round 4
// 301.964 us; speedup vs baseline: 2.1293x; 1.4199x over previous
//
#include <hip/hip_runtime.h>
#include <math.h>

#define NQ 16
#define NLAYERS 3
#define NSTATES 65536   // 2^16
#define BATCH 256

// Clamped global read: any harness/size mismatch becomes a wrong value,
// never an OOB fault.
__device__ __forceinline__ float rd(const float* __restrict__ p, int i, int n) {
    return p[i < n ? i : (n - 1)];
}

// ---------------------------------------------------------------------------
// static_for with compile-time indices.
// ---------------------------------------------------------------------------
template <int I> struct IC { static constexpr int v = I; };

template <int I, int N, typename F>
__device__ __forceinline__ void sfor_i(F& f) {
    if constexpr (I < N) {
        f(IC<I>{});
        sfor_i<I + 1, N>(f);
    }
}
template <int N, typename F>
__device__ __forceinline__ void sfor(F&& f) { sfor_i<0, N>(f); }

// noisy-CNOT symmetric mix: a' = (1-p)a + pb ; b' = (1-p)b + pa
__device__ __forceinline__ void mix2(float& a, float& b, float p) {
    float na = (1.f - p) * a + p * b;
    float nb = (1.f - p) * b + p * a;
    a = na; b = nb;
}
// single-qubit butterfly on a pair (a0 = bit clear, a1 = bit set)
__device__ __forceinline__ void bf2(float& a0, float& a1, float4 m) {
    float n0 = m.x * a0 + m.y * a1;
    float n1 = m.z * a0 + m.w * a1;
    a0 = n0; a1 = n1;
}

// ---------------------------------------------------------------------------
// R4 REDESIGN: the compiler pins the VGPR budget at 64 for 1024-thread blocks
// (verified across launch_bounds / waves_per_eu / amdgpu_num_vgpr / LDS-forced
// occupancy in R0-R3) and 64 state floats can never fit -> mandatory scratch
// spill (~1.3 GB HBM/dispatch == the entire runtime). So: SPLIT THE STATE.
//   bits 0..5   = lane bits (tid)   -> __shfl_xor
//   bits 6..9   = wave bits (tid)   -> barriered LDS exchange windows
//   bits 10..14 = register bits     -> r[32] in VGPRs (fits the 64 budget)
//   bit  15     = LDS bit           -> ldsS[jj*1024+tid], 128 KiB, THREAD-LOCAL
// All gates touching bit 10..15 pairs are thread-private (no races/barriers).
// Lane-bit gates on the LDS half are chunk-fused: load 8 -> all commuting
// gates via shfl -> store 8. Only wave-bit gates need barriers (r/w windows).
// Live set ~55 VGPRs -> zero scratch by construction.
// ---------------------------------------------------------------------------

// Wave-bit gate (own' = A*own + B*partner_val) applied to both halves.
// mask = 1<<q (q in 6..9). 8 windows x {stage 4 reg elems through xb +
// direct-pair reads of 4 LDS elems} with 2 barriers per window.
__device__ __forceinline__ void wave_mix(float (&r)[32], float* ldsS, float* xb,
                                         int tid, int mask, float A, float B) {
    const int partner = tid ^ mask;
    sfor<8>([&](auto C) {
        sfor<4>([&](auto K) { xb[K.v * 1024 + tid] = r[C.v * 4 + K.v]; });
        float own[4], prt[4];
        sfor<4>([&](auto K) {
            own[K.v] = ldsS[(C.v * 4 + K.v) * 1024 + tid];
            prt[K.v] = ldsS[(C.v * 4 + K.v) * 1024 + partner];
        });
        __syncthreads();
        sfor<4>([&](auto K) {
            float pr = xb[K.v * 1024 + partner];
            r[C.v * 4 + K.v] = A * r[C.v * 4 + K.v] + B * pr;
            ldsS[(C.v * 4 + K.v) * 1024 + tid] = A * own[K.v] + B * prt[K.v];
        });
        __syncthreads();
    });
}

__global__
__attribute__((amdgpu_flat_work_group_size(1024, 1024)))
void qsim(const float* __restrict__ x,
          const float* __restrict__ rot,
          const float* __restrict__ ent,
          const float* __restrict__ W1,
          const float* __restrict__ b1,
          const float* __restrict__ W2,
          const float* __restrict__ b2,
          float* __restrict__ out,
          long long out_floats,
          int nx, int nrot, int nent, int nW1, int nb1, int nW2, int nb2) {
    const int tid = threadIdx.x;
    const int b   = blockIdx.x;

    __shared__ float  ldsS[32 * 1024];         // 128 KiB: bit15=1 half of state
    __shared__ float  xb[4 * 1024];            // 16 KiB exchange buffer
    __shared__ float4 Mg[NLAYERS * NQ];        // 48 gate matrices
    __shared__ float  pg[NLAYERS * (NQ - 1)];  // 45 CNOT mix probs
    __shared__ float  hidS[64];
    __shared__ float  hqS[16];

    // ---- zero-init LDS half (thread-local slots) ----
    sfor<32>([&](auto J) { ldsS[J.v * 1024 + tid] = 0.f; });

    // ---- Phase A: MLP hidden layer (64 threads) + sigmoid probs ----
    if (tid < 64) {
        float s = rd(b1, tid, nb1);
        for (int k = 0; k < 100; k++)
            s = fmaf(rd(x, b * 100 + k, nx), rd(W1, k * 64 + tid, nW1), s);
        hidS[tid] = fmaxf(s, 0.f);
    } else if (tid >= 64 && tid < 64 + NLAYERS * (NQ - 1)) {
        int i = tid - 64;
        pg[i] = 1.f / (1.f + expf(-rd(ent, i, nent)));
    }
    __syncthreads();

    // ---- Phase B: output layer hq (16 threads) ----
    if (tid < 16) {
        float s = rd(b2, tid, nb2);
#pragma unroll
        for (int i = 0; i < 64; i++)
            s = fmaf(hidS[i], rd(W2, i * 16 + tid, nW2), s);
        hqS[tid] = tanhf(s);
    }
    __syncthreads();

    // ---- Phase C: gate matrices (48 threads) ----
    if (tid < NLAYERS * NQ) {
        int q = tid & 15;
        float hv = hqS[q];
        float a0 = 0.5f * rd(rot, tid * 3 + 0, nrot) * hv;
        float a1 = 0.5f * rd(rot, tid * 3 + 1, nrot) * hv;
        float a2 = 0.5f * rd(rot, tid * 3 + 2, nrot) * hv;
        float cx = cosf(a0), sx = sinf(a0);
        float cy = cosf(a1), sy = sinf(a1);
        float cz = cosf(a2), sz = sinf(a2);
        Mg[tid] = make_float4(cx * cy * cz, -(sx * sy * sz),
                              sx * sy * cz,  cx * cy * sz);
    }
    __syncthreads();

    // ---- statevector init: |0...0> (element 0: bit15=0, jj=0, tid=0) ----
    float r[32];
    sfor<32>([&](auto J) { r[J.v] = 0.f; });
    if (tid == 0) r[0] = 1.f;

    for (int l = 0; l < NLAYERS; l++) {
        // ======== (1) single-qubit gates, lane bits q=0..5 ========
        // register half: shfl butterflies, fenced in chunks of 8
#pragma unroll
        for (int q = 0; q < 6; q++) {
            float4 m = Mg[l * NQ + q];
            int bit = (tid >> q) & 1;
            float cown  = bit ? m.w : m.x;
            float cpart = bit ? m.z : m.y;
            sfor<4>([&](auto C) {
                sfor<8>([&](auto K) {
                    constexpr int j = C.v * 8 + K.v;
                    float part = __shfl_xor(r[j], 1 << q);
                    r[j] = cown * r[j] + cpart * part;
                });
                __builtin_amdgcn_sched_barrier(0);
            });
        }
        // LDS half: chunk-fused over all 6 commuting gates (thread-local LDS)
        sfor<4>([&](auto C) {
            float t[8];
            sfor<8>([&](auto K) { t[K.v] = ldsS[(C.v * 8 + K.v) * 1024 + tid]; });
#pragma unroll
            for (int q = 0; q < 6; q++) {
                float4 m = Mg[l * NQ + q];
                int bit = (tid >> q) & 1;
                float cown  = bit ? m.w : m.x;
                float cpart = bit ? m.z : m.y;
                sfor<8>([&](auto K) {
                    float part = __shfl_xor(t[K.v], 1 << q);
                    t[K.v] = cown * t[K.v] + cpart * part;
                });
            }
            sfor<8>([&](auto K) { ldsS[(C.v * 8 + K.v) * 1024 + tid] = t[K.v]; });
        });

        __syncthreads();  // other waves will read our ldsS slots next

        // ======== (2) single-qubit gates, wave bits q=6..9 ========
        for (int q = 6; q < 10; q++) {
            float4 m = Mg[l * NQ + q];
            int bit = (tid >> q) & 1;
            float A = bit ? m.w : m.x;
            float B = bit ? m.z : m.y;
            wave_mix(r, ldsS, xb, tid, 1 << q, A, B);
        }

        // ======== (3) single-qubit gates, register bits q=10..15 ========
        // register-half butterflies q10..14 (h = 1,2,4,8,16)
        sfor<5>([&](auto QQ) {
            float4 m = Mg[l * NQ + 10 + QQ.v];
            sfor<32>([&](auto J) {
                constexpr int h = 1 << QQ.v;
                if constexpr (!(J.v & h)) bf2(r[J.v], r[J.v | h], m);
            });
        });
        {
            float4 m15 = Mg[l * NQ + 15];
            // pass A: l[0..15]: q10..13 within + q15 pairs (r[j], l[j])
            {
                float t[16];
                sfor<16>([&](auto K) { t[K.v] = ldsS[K.v * 1024 + tid]; });
                sfor<4>([&](auto BB) {
                    float4 m = Mg[l * NQ + 10 + BB.v];
                    sfor<16>([&](auto J) {
                        constexpr int h = 1 << BB.v;
                        if constexpr (!(J.v & h)) bf2(t[J.v], t[J.v | h], m);
                    });
                });
                sfor<16>([&](auto K) { bf2(r[K.v], t[K.v], m15); });
                sfor<16>([&](auto K) { ldsS[K.v * 1024 + tid] = t[K.v]; });
            }
            // pass B: l[16..31]
            {
                float t[16];
                sfor<16>([&](auto K) { t[K.v] = ldsS[(16 + K.v) * 1024 + tid]; });
                sfor<4>([&](auto BB) {
                    float4 m = Mg[l * NQ + 10 + BB.v];
                    sfor<16>([&](auto J) {
                        constexpr int h = 1 << BB.v;
                        if constexpr (!(J.v & h)) bf2(t[J.v], t[J.v | h], m);
                    });
                });
                sfor<16>([&](auto K) { bf2(r[16 + K.v], t[K.v], m15); });
                sfor<16>([&](auto K) { ldsS[(16 + K.v) * 1024 + tid] = t[K.v]; });
            }
            // pass C/D: q14 on LDS half, pairs (l[jj], l[jj+16])
            {
                float4 m14 = Mg[l * NQ + 14];
                float t[16];
                sfor<8>([&](auto K) {
                    t[K.v]     = ldsS[K.v * 1024 + tid];
                    t[8 + K.v] = ldsS[(16 + K.v) * 1024 + tid];
                });
                sfor<8>([&](auto K) { bf2(t[K.v], t[8 + K.v], m14); });
                sfor<8>([&](auto K) {
                    ldsS[K.v * 1024 + tid]        = t[K.v];
                    ldsS[(16 + K.v) * 1024 + tid] = t[8 + K.v];
                });
                sfor<8>([&](auto K) {
                    t[K.v]     = ldsS[(8 + K.v) * 1024 + tid];
                    t[8 + K.v] = ldsS[(24 + K.v) * 1024 + tid];
                });
                sfor<8>([&](auto K) { bf2(t[K.v], t[8 + K.v], m14); });
                sfor<8>([&](auto K) {
                    ldsS[(8 + K.v) * 1024 + tid]  = t[K.v];
                    ldsS[(24 + K.v) * 1024 + tid] = t[8 + K.v];
                });
            }
        }

        // ======== (4) noisy CNOTs, lane targets: c=0..4 (tgt bits 1..5) ====
        // register half: sequential shfl mixes
#pragma unroll
        for (int c = 0; c < 5; c++) {
            float p = pg[l * (NQ - 1) + c];
            int ctrl = (tid >> c) & 1;
            float pc = ctrl ? p : 0.f;
            float qc = ctrl ? (1.f - p) : 1.f;
            sfor<4>([&](auto C) {
                sfor<8>([&](auto K) {
                    constexpr int j = C.v * 8 + K.v;
                    float f = __shfl_xor(r[j], 1 << (c + 1));
                    r[j] = qc * r[j] + pc * f;
                });
                __builtin_amdgcn_sched_barrier(0);
            });
        }
        // LDS half: chunk-fused over c=0..4 IN ORDER
        sfor<4>([&](auto C) {
            float t[8];
            sfor<8>([&](auto K) { t[K.v] = ldsS[(C.v * 8 + K.v) * 1024 + tid]; });
#pragma unroll
            for (int c = 0; c < 5; c++) {
                float p = pg[l * (NQ - 1) + c];
                int ctrl = (tid >> c) & 1;
                float pc = ctrl ? p : 0.f;
                float qc = ctrl ? (1.f - p) : 1.f;
                sfor<8>([&](auto K) {
                    float f = __shfl_xor(t[K.v], 1 << (c + 1));
                    t[K.v] = qc * t[K.v] + pc * f;
                });
            }
            sfor<8>([&](auto K) { ldsS[(C.v * 8 + K.v) * 1024 + tid] = t[K.v]; });
        });

        __syncthreads();  // wave windows read partner slots next

        // ======== (5) noisy CNOTs, wave targets: c=5..8 (tgt bits 6..9) ====
        for (int c = 5; c < 9; c++) {
            float p = pg[l * (NQ - 1) + c];
            int ctrl = (tid >> c) & 1;
            float pc = ctrl ? p : 0.f;
            float qc = ctrl ? (1.f - p) : 1.f;
            wave_mix(r, ldsS, xb, tid, 1 << (c + 1), qc, pc);
        }

        // ======== (6) noisy CNOTs, register targets: c=9..14 ========
        {
            float p9 = pg[l * (NQ - 1) + 9];
            int ctrl9 = (tid >> 9) & 1;
            // register half, chain order c9 -> c13
            if (ctrl9) {
                sfor<16>([&](auto T) { mix2(r[2 * T.v], r[2 * T.v + 1], p9); });
            }
            sfor<4>([&](auto BB) {
                float p = pg[l * (NQ - 1) + 10 + BB.v];
                sfor<32>([&](auto J) {
                    constexpr int cm = 1 << BB.v;
                    constexpr int tm = 2 << BB.v;
                    if constexpr ((J.v & cm) && !(J.v & tm))
                        mix2(r[J.v], r[J.v | tm], p);
                });
            });
            // LDS half pass E: l[0..15]: c9 (if ctrl), c10..12
            {
                float t[16];
                sfor<16>([&](auto K) { t[K.v] = ldsS[K.v * 1024 + tid]; });
                if (ctrl9) {
                    sfor<8>([&](auto T) { mix2(t[2 * T.v], t[2 * T.v + 1], p9); });
                }
                sfor<3>([&](auto BB) {
                    float p = pg[l * (NQ - 1) + 10 + BB.v];
                    sfor<16>([&](auto J) {
                        constexpr int cm = 1 << BB.v;
                        constexpr int tm = 2 << BB.v;
                        if constexpr ((J.v & cm) && !(J.v & tm))
                            mix2(t[J.v], t[J.v | tm], p);
                    });
                });
                sfor<16>([&](auto K) { ldsS[K.v * 1024 + tid] = t[K.v]; });
            }
            // LDS half pass F: l[16..31]: same c9..c12
            {
                float t[16];
                sfor<16>([&](auto K) { t[K.v] = ldsS[(16 + K.v) * 1024 + tid]; });
                if (ctrl9) {
                    sfor<8>([&](auto T) { mix2(t[2 * T.v], t[2 * T.v + 1], p9); });
                }
                sfor<3>([&](auto BB) {
                    float p = pg[l * (NQ - 1) + 10 + BB.v];
                    sfor<16>([&](auto J) {
                        constexpr int cm = 1 << BB.v;
                        constexpr int tm = 2 << BB.v;
                        if constexpr ((J.v & cm) && !(J.v & tm))
                            mix2(t[J.v], t[J.v | tm], p);
                    });
                });
                sfor<16>([&](auto K) { ldsS[(16 + K.v) * 1024 + tid] = t[K.v]; });
            }
            // pass G: c13 pairs (l[8..15], l[24..31]); then c14 on jj=24..31
            {
                float p13 = pg[l * (NQ - 1) + 13];
                float p14 = pg[l * (NQ - 1) + 14];
                float t[16];
                sfor<8>([&](auto K) {
                    t[K.v]     = ldsS[(8 + K.v) * 1024 + tid];
                    t[8 + K.v] = ldsS[(24 + K.v) * 1024 + tid];
                });
                sfor<8>([&](auto K) { mix2(t[K.v], t[8 + K.v], p13); });
                sfor<8>([&](auto K) { mix2(r[24 + K.v], t[8 + K.v], p14); });
                sfor<8>([&](auto K) {
                    ldsS[(8 + K.v) * 1024 + tid]  = t[K.v];
                    ldsS[(24 + K.v) * 1024 + tid] = t[8 + K.v];
                });
                // pass H: c14 on jj=16..23 (untouched by c13)
                float t2[8];
                sfor<8>([&](auto K) { t2[K.v] = ldsS[(16 + K.v) * 1024 + tid]; });
                sfor<8>([&](auto K) { mix2(r[16 + K.v], t2[K.v], p14); });
                sfor<8>([&](auto K) { ldsS[(16 + K.v) * 1024 + tid] = t2[K.v]; });
            }
        }
    }

    // ---------------- output: dense float32 real parts ----------------
    long long base = (long long)b * NSTATES;
    sfor<32>([&](auto J) {
        long long fi = base + (long long)(J.v * 1024) + tid;
        if (fi < out_floats) out[fi] = r[J.v];
    });
    sfor<32>([&](auto J) {
        long long fi = base + 32768LL + (long long)(J.v * 1024) + tid;
        float v = ldsS[J.v * 1024 + tid];
        if (fi < out_floats) out[fi] = v;
    });
}

extern "C" void kernel_launch(void* const* d_in, const int* in_sizes, int n_in,
                              void* d_out, int out_size, void* d_ws, size_t ws_size,
                              hipStream_t stream) {
    const float* x   = (const float*)d_in[0];
    const float* rot = (const float*)d_in[1];
    const float* ent = (const float*)d_in[2];
    const float* W1  = (const float*)d_in[3];
    const float* b1  = (const float*)d_in[4];
    const float* W2  = (const float*)d_in[5];
    const float* b2  = (const float*)d_in[6];

    qsim<<<BATCH, 1024, 0, stream>>>(x, rot, ent, W1, b1, W2, b2,
                                     (float*)d_out, (long long)out_size,
                                     in_sizes[0], in_sizes[1], in_sizes[2],
                                     in_sizes[3], in_sizes[4], in_sizes[5],
                                     in_sizes[6]);
}

// Round 5
// 244.746 us; speedup vs baseline: 2.6270x; 1.2338x over previous
//
#include <hip/hip_runtime.h>
#include <math.h>

#define NQ 16
#define NLAYERS 3
#define NSTATES 65536   // 2^16
#define BATCH 256

// Clamped global read: any harness/size mismatch becomes a wrong value,
// never an OOB fault.
__device__ __forceinline__ float rd(const float* __restrict__ p, int i, int n) {
    return p[i < n ? i : (n - 1)];
}

// ---------------------------------------------------------------------------
// static_for with compile-time indices (keeps every state subscript literal).
// ---------------------------------------------------------------------------
template <int I> struct IC { static constexpr int v = I; };

template <int I, int N, typename F>
__device__ __forceinline__ void sfor_i(F& f) {
    if constexpr (I < N) {
        f(IC<I>{});
        sfor_i<I + 1, N>(f);
    }
}
template <int N, typename F>
__device__ __forceinline__ void sfor(F&& f) { sfor_i<0, N>(f); }

// noisy-CNOT symmetric mix: a' = (1-p)a + pb ; b' = (1-p)b + pa
__device__ __forceinline__ void mix2(float& a, float& b, float p) {
    float na = (1.f - p) * a + p * b;
    float nb = (1.f - p) * b + p * a;
    a = na; b = nb;
}
// single-qubit butterfly on a pair (a0 = bit clear, a1 = bit set)
__device__ __forceinline__ void bf2(float& a0, float& a1, float4 m) {
    float n0 = m.x * a0 + m.y * a1;
    float n1 = m.z * a0 + m.w * a1;
    a0 = n0; a1 = n1;
}

// ---------------------------------------------------------------------------
// R5: DS-pipe issue-bound (R4 model match: ~1650 b32 + 700 bpermute per
// thread-layer ~= 245us). Replace the 8 wave_mix exchange gates (1280 b32)
// with TWO bit-transposes per layer swapping state bits 6..9 <-> 10..13.
//
// Layout A (natural): element e = sA*1024 + tid.
//   sA in [0,32)  -> r[sA]        (VGPR half, b15=0)
//   sA in [32,64) -> ldsS[(sA-32)*1024 + tid]   (LDS half, b15=1)
//   slot bits: sA = 16*b14 + 8*b13 + 4*b12 + 2*b11 + b10 (+32 if b15)
// Layout B (after T1): thread u = (b13..b10)*64 + (b5..b0),
//   slot sB = 16*b14 + (b9..b6)  (+32 if b15)
// T1/T2 are the same involution. Reg half goes through a 16 KiB scratch in
// 4-slot sub-chunks (readers = whole waves, hold 16 floats until all staged);
// LDS half transposes in place per 16-row region: all threads cross-read
// rows (stride-64, conflict-free: addr%32==lane%32), one barrier, write own
// column. Gates q6..9 (+q15) fuse into T1's gather; c9..12 into T2's.
//
// Per-layer DS ops: ~512 b32 + 704 bpermute (vs R4's ~1650+700); barriers
// ~40 (vs ~134). Predicted ~150 us.
// ---------------------------------------------------------------------------
__global__
__attribute__((amdgpu_flat_work_group_size(1024, 1024)))
void qsim(const float* __restrict__ x,
          const float* __restrict__ rot,
          const float* __restrict__ ent,
          const float* __restrict__ W1,
          const float* __restrict__ b1,
          const float* __restrict__ W2,
          const float* __restrict__ b2,
          float* __restrict__ out,
          long long out_floats,
          int nx, int nrot, int nent, int nW1, int nb1, int nW2, int nb2) {
    const int tid  = threadIdx.x;
    const int b    = blockIdx.x;
    const int lane = tid & 63;
    const int wave = tid >> 6;        // = (b13..b10) of this thread's elements (A) / (b9..b6) (B)
    const int wq   = (tid >> 8) & 3;  // sub-chunk selector for transpose reads
    const int wv   = (tid >> 6) & 3;  // v-index for transpose reads

    __shared__ float  ldsS[32 * 1024];         // 128 KiB: b15=1 half of state
    __shared__ float  scr[4 * 1024];           // 16 KiB transpose bounce
    __shared__ float4 Mg[NLAYERS * NQ];        // 48 gate matrices
    __shared__ float  pg[NLAYERS * (NQ - 1)];  // 45 CNOT mix probs
    __shared__ float  hidS[64];
    __shared__ float  hqS[16];

    // ---- zero-init LDS half (thread-local columns) ----
    sfor<32>([&](auto J) { ldsS[J.v * 1024 + tid] = 0.f; });

    // ---- Phase A: MLP hidden layer (64 threads) + sigmoid probs ----
    if (tid < 64) {
        float s = rd(b1, tid, nb1);
        for (int k = 0; k < 100; k++)
            s = fmaf(rd(x, b * 100 + k, nx), rd(W1, k * 64 + tid, nW1), s);
        hidS[tid] = fmaxf(s, 0.f);
    } else if (tid >= 64 && tid < 64 + NLAYERS * (NQ - 1)) {
        int i = tid - 64;
        pg[i] = 1.f / (1.f + expf(-rd(ent, i, nent)));
    }
    __syncthreads();

    // ---- Phase B: output layer hq (16 threads) ----
    if (tid < 16) {
        float s = rd(b2, tid, nb2);
#pragma unroll
        for (int i = 0; i < 64; i++)
            s = fmaf(hidS[i], rd(W2, i * 16 + tid, nW2), s);
        hqS[tid] = tanhf(s);
    }
    __syncthreads();

    // ---- Phase C: gate matrices (48 threads) ----
    if (tid < NLAYERS * NQ) {
        int q = tid & 15;
        float hv = hqS[q];
        float a0 = 0.5f * rd(rot, tid * 3 + 0, nrot) * hv;
        float a1 = 0.5f * rd(rot, tid * 3 + 1, nrot) * hv;
        float a2 = 0.5f * rd(rot, tid * 3 + 2, nrot) * hv;
        float cx = cosf(a0), sx = sinf(a0);
        float cy = cosf(a1), sy = sinf(a1);
        float cz = cosf(a2), sz = sinf(a2);
        Mg[tid] = make_float4(cx * cy * cz, -(sx * sy * sz),
                              sx * sy * cz,  cx * cy * sz);
    }
    __syncthreads();

    // ---- statevector init: |0...0> ----
    float r[32];
    sfor<32>([&](auto J) { r[J.v] = 0.f; });
    if (tid == 0) r[0] = 1.f;

    for (int l = 0; l < NLAYERS; l++) {
        // ================== [A] single-qubit gates ==================
        // reg half, q0..5 (lane bits): shfl chunks of 8 + fence
#pragma unroll
        for (int q = 0; q < 6; q++) {
            float4 m = Mg[l * NQ + q];
            int bit = (tid >> q) & 1;
            float cown  = bit ? m.w : m.x;
            float cpart = bit ? m.z : m.y;
            sfor<4>([&](auto C) {
                sfor<8>([&](auto K) {
                    constexpr int j = C.v * 8 + K.v;
                    float part = __shfl_xor(r[j], 1 << q);
                    r[j] = cown * r[j] + cpart * part;
                });
                __builtin_amdgcn_sched_barrier(0);
            });
        }
        // reg half, q10..14 (slot bits): in-register butterflies
        sfor<5>([&](auto QQ) {
            float4 m = Mg[l * NQ + 10 + QQ.v];
            sfor<32>([&](auto J) {
                constexpr int h = 1 << QQ.v;
                if constexpr (!(J.v & h)) bf2(r[J.v], r[J.v | h], m);
            });
        });
        // lds half PASS1: 4 windows of 8 consecutive rows: q0..5 (shfl) +
        // q10..12 (row bits 0..2). Column-local -> no barriers.
        sfor<4>([&](auto W) {
            float t[8];
            sfor<8>([&](auto K) { t[K.v] = ldsS[(W.v * 8 + K.v) * 1024 + tid]; });
#pragma unroll
            for (int q = 0; q < 6; q++) {
                float4 m = Mg[l * NQ + q];
                int bit = (tid >> q) & 1;
                float cown  = bit ? m.w : m.x;
                float cpart = bit ? m.z : m.y;
                sfor<8>([&](auto K) {
                    float part = __shfl_xor(t[K.v], 1 << q);
                    t[K.v] = cown * t[K.v] + cpart * part;
                });
                __builtin_amdgcn_sched_barrier(0);
            }
            sfor<3>([&](auto QQ) {
                float4 m = Mg[l * NQ + 10 + QQ.v];
                sfor<8>([&](auto K) {
                    constexpr int h = 1 << QQ.v;
                    if constexpr (!(K.v & h)) bf2(t[K.v], t[K.v | h], m);
                });
            });
            sfor<8>([&](auto K) { ldsS[(W.v * 8 + K.v) * 1024 + tid] = t[K.v]; });
        });
        // lds half PASS2: 8 windows of 4 rows {j, 8+j, 16+j, 24+j}: q13 (+-8),
        // q14 (+-16). Column-local.
        {
            float4 m13 = Mg[l * NQ + 13];
            float4 m14 = Mg[l * NQ + 14];
            sfor<8>([&](auto J) {
                float t0 = ldsS[(J.v)      * 1024 + tid];
                float t1 = ldsS[(8 + J.v)  * 1024 + tid];
                float t2 = ldsS[(16 + J.v) * 1024 + tid];
                float t3 = ldsS[(24 + J.v) * 1024 + tid];
                bf2(t0, t1, m13); bf2(t2, t3, m13);
                bf2(t0, t2, m14); bf2(t1, t3, m14);
                ldsS[(J.v)      * 1024 + tid] = t0;
                ldsS[(8 + J.v)  * 1024 + tid] = t1;
                ldsS[(16 + J.v) * 1024 + tid] = t2;
                ldsS[(24 + J.v) * 1024 + tid] = t3;
            });
        }

        // ================== T1: A->B, fused q6..9 (+q15) ==================
        sfor<2>([&](auto B14) {
            // ---- reg half through scratch, 4-slot sub-chunks ----
            float val[16];
            sfor<4>([&](auto J) {
                sfor<4>([&](auto V) {
                    scr[V.v * 1024 + tid] = r[B14.v * 16 + J.v * 4 + V.v];
                });
                __syncthreads();
                if (wq == J.v) {
                    sfor<16>([&](auto G) {
                        val[G.v] = scr[wv * 1024 + G.v * 64 + lane];
                    });
                }
                __syncthreads();
            });
            // q6..9 butterflies over g-bits
            sfor<4>([&](auto Q) {
                float4 m = Mg[l * NQ + 6 + Q.v];
                sfor<16>([&](auto G) {
                    constexpr int h = 1 << Q.v;
                    if constexpr (!(G.v & h)) bf2(val[G.v], val[G.v | h], m);
                });
                __builtin_amdgcn_sched_barrier(0);
            });
            sfor<16>([&](auto G) { r[B14.v * 16 + G.v] = val[G.v]; });

            // ---- lds half in place: cross-read rows, barrier, write own col
            float vL[16];
            {
                const int srow = B14.v * 16 + wave;
                sfor<16>([&](auto G) {
                    vL[G.v] = ldsS[srow * 1024 + G.v * 64 + lane];
                });
            }
            sfor<4>([&](auto Q) {
                float4 m = Mg[l * NQ + 6 + Q.v];
                sfor<16>([&](auto G) {
                    constexpr int h = 1 << Q.v;
                    if constexpr (!(G.v & h)) bf2(vL[G.v], vL[G.v | h], m);
                });
                __builtin_amdgcn_sched_barrier(0);
            });
            {   // q15: pairs (reg, lds) at same (b14, g)
                float4 m15 = Mg[l * NQ + 15];
                sfor<16>([&](auto G) { bf2(r[B14.v * 16 + G.v], vL[G.v], m15); });
            }
            __syncthreads();   // all cross-column reads of this 16-row region done
            sfor<16>([&](auto G) {
                ldsS[(B14.v * 16 + G.v) * 1024 + tid] = vL[G.v];
            });
        });

        // ================== [B] CNOTs c0..8 ==================
        // reg: c0..4 (lane ctrl, lane tgt) in order, shfl chunks of 8
#pragma unroll
        for (int c = 0; c < 5; c++) {
            float p = pg[l * (NQ - 1) + c];
            int ctl = (tid >> c) & 1;
            float pc = ctl ? p : 0.f;
            float qc = ctl ? (1.f - p) : 1.f;
            sfor<4>([&](auto C) {
                sfor<8>([&](auto K) {
                    constexpr int j = C.v * 8 + K.v;
                    float f = __shfl_xor(r[j], 1 << (c + 1));
                    r[j] = qc * r[j] + pc * f;
                });
                __builtin_amdgcn_sched_barrier(0);
            });
        }
        // reg: c5 (ctrl lane bit5, tgt g-bit0)
        {
            float p = pg[l * (NQ - 1) + 5];
            int ctl = (tid >> 5) & 1;
            float pc = ctl ? p : 0.f;
            float qc = ctl ? (1.f - p) : 1.f;
            sfor<2>([&](auto B14) { sfor<16>([&](auto G) {
                if constexpr (!(G.v & 1)) {
                    constexpr int i0 = B14.v * 16 + G.v, i1 = i0 | 1;
                    float a = r[i0], c2 = r[i1];
                    r[i0] = qc * a + pc * c2;
                    r[i1] = qc * c2 + pc * a;
                }
            }); });
        }
        // reg: c6..8 (ctrl g-bit CC, tgt g-bit CC+1)
        sfor<3>([&](auto CC) {
            float p = pg[l * (NQ - 1) + 6 + CC.v];
            sfor<2>([&](auto B14) { sfor<16>([&](auto G) {
                constexpr int cm = 1 << CC.v;
                constexpr int tm = 2 << CC.v;
                if constexpr ((G.v & cm) && !(G.v & tm))
                    mix2(r[B14.v * 16 + G.v], r[B14.v * 16 + (G.v | tm)], p);
            }); });
        });
        // lds: per-b14 window of 16 rows: c0..4 (shfl) then c5..8. Column-local.
        sfor<2>([&](auto B14) {
            float t[16];
            sfor<16>([&](auto G) { t[G.v] = ldsS[(B14.v * 16 + G.v) * 1024 + tid]; });
#pragma unroll
            for (int c = 0; c < 5; c++) {
                float p = pg[l * (NQ - 1) + c];
                int ctl = (tid >> c) & 1;
                float pc = ctl ? p : 0.f;
                float qc = ctl ? (1.f - p) : 1.f;
                sfor<2>([&](auto HB) {
                    sfor<8>([&](auto K) {
                        constexpr int g = HB.v * 8 + K.v;
                        float f = __shfl_xor(t[g], 1 << (c + 1));
                        t[g] = qc * t[g] + pc * f;
                    });
                    __builtin_amdgcn_sched_barrier(0);
                });
            }
            {
                float p = pg[l * (NQ - 1) + 5];
                int ctl = (tid >> 5) & 1;
                float pc = ctl ? p : 0.f;
                float qc = ctl ? (1.f - p) : 1.f;
                sfor<16>([&](auto G) {
                    if constexpr (!(G.v & 1)) {
                        float a = t[G.v], c2 = t[G.v | 1];
                        t[G.v]     = qc * a + pc * c2;
                        t[G.v | 1] = qc * c2 + pc * a;
                    }
                });
            }
            sfor<3>([&](auto CC) {
                float p = pg[l * (NQ - 1) + 6 + CC.v];
                sfor<16>([&](auto G) {
                    constexpr int cm = 1 << CC.v;
                    constexpr int tm = 2 << CC.v;
                    if constexpr ((G.v & cm) && !(G.v & tm))
                        mix2(t[G.v], t[G.v | tm], p);
                });
            });
            sfor<16>([&](auto G) { ldsS[(B14.v * 16 + G.v) * 1024 + tid] = t[G.v]; });
        });

        // ================== T2: B->A, fused c9..12 ==================
        {
            float p9  = pg[l * (NQ - 1) + 9];
            int  cb9  = (tid >> 9) & 1;
            float pc9 = cb9 ? p9 : 0.f;
            float qc9 = cb9 ? (1.f - p9) : 1.f;

            sfor<2>([&](auto B14) {
                float val[16];
                sfor<4>([&](auto J) {
                    sfor<4>([&](auto V) {
                        scr[V.v * 1024 + tid] = r[B14.v * 16 + J.v * 4 + V.v];
                    });
                    __syncthreads();
                    if (wq == J.v) {
                        sfor<16>([&](auto H) {
                            val[H.v] = scr[wv * 1024 + H.v * 64 + lane];
                        });
                    }
                    __syncthreads();
                });
                // c9 (ctrl = thread bit 9), then c10..12 over h-bits
                sfor<16>([&](auto H) {
                    if constexpr (!(H.v & 1)) {
                        float a = val[H.v], c2 = val[H.v | 1];
                        val[H.v]     = qc9 * a + pc9 * c2;
                        val[H.v | 1] = qc9 * c2 + pc9 * a;
                    }
                });
                sfor<3>([&](auto CC) {
                    float p = pg[l * (NQ - 1) + 10 + CC.v];
                    sfor<16>([&](auto H) {
                        constexpr int cm = 1 << CC.v;
                        constexpr int tm = 2 << CC.v;
                        if constexpr ((H.v & cm) && !(H.v & tm))
                            mix2(val[H.v], val[H.v | tm], p);
                    });
                });
                sfor<16>([&](auto H) { r[B14.v * 16 + H.v] = val[H.v]; });

                float vL[16];
                {
                    const int srow = B14.v * 16 + wave;
                    sfor<16>([&](auto H) {
                        vL[H.v] = ldsS[srow * 1024 + H.v * 64 + lane];
                    });
                }
                sfor<16>([&](auto H) {
                    if constexpr (!(H.v & 1)) {
                        float a = vL[H.v], c2 = vL[H.v | 1];
                        vL[H.v]     = qc9 * a + pc9 * c2;
                        vL[H.v | 1] = qc9 * c2 + pc9 * a;
                    }
                });
                sfor<3>([&](auto CC) {
                    float p = pg[l * (NQ - 1) + 10 + CC.v];
                    sfor<16>([&](auto H) {
                        constexpr int cm = 1 << CC.v;
                        constexpr int tm = 2 << CC.v;
                        if constexpr ((H.v & cm) && !(H.v & tm))
                            mix2(vL[H.v], vL[H.v | tm], p);
                    });
                });
                __syncthreads();   // all cross-reads of this 16-row region done
                sfor<16>([&](auto H) {
                    ldsS[(B14.v * 16 + H.v) * 1024 + tid] = vL[H.v];
                });
            });
        }

        // ================== [A] c13, c14 (column-local) ==================
        {
            float p13 = pg[l * (NQ - 1) + 13];
            // reg: ctrl b13 (slot bit 3) = 1 -> pairs (s, s+16) for s in 8..15
            sfor<8>([&](auto K) { mix2(r[8 + K.v], r[24 + K.v], p13); });
            // lds: rows {8..15} <-> {24..31}
            sfor<8>([&](auto K) {
                float a = ldsS[(8 + K.v)  * 1024 + tid];
                float c2 = ldsS[(24 + K.v) * 1024 + tid];
                mix2(a, c2, p13);
                ldsS[(8 + K.v)  * 1024 + tid] = a;
                ldsS[(24 + K.v) * 1024 + tid] = c2;
            });
        }
        {
            float p14 = pg[l * (NQ - 1) + 14];
            // ctrl b14 (slot bit 4) = 1 -> pairs (reg slot 16+k, lds row 16+k)
            sfor<16>([&](auto K) {
                float v = ldsS[(16 + K.v) * 1024 + tid];
                mix2(r[16 + K.v], v, p14);
                ldsS[(16 + K.v) * 1024 + tid] = v;
            });
        }
    }

    // ---------------- output: dense float32 real parts ----------------
    long long base = (long long)b * NSTATES;
    sfor<32>([&](auto J) {
        long long fi = base + (long long)(J.v * 1024) + tid;
        if (fi < out_floats) out[fi] = r[J.v];
    });
    sfor<32>([&](auto J) {
        long long fi = base + 32768LL + (long long)(J.v * 1024) + tid;
        float v = ldsS[J.v * 1024 + tid];
        if (fi < out_floats) out[fi] = v;
    });
}

extern "C" void kernel_launch(void* const* d_in, const int* in_sizes, int n_in,
                              void* d_out, int out_size, void* d_ws, size_t ws_size,
                              hipStream_t stream) {
    const float* x   = (const float*)d_in[0];
    const float* rot = (const float*)d_in[1];
    const float* ent = (const float*)d_in[2];
    const float* W1  = (const float*)d_in[3];
    const float* b1  = (const float*)d_in[4];
    const float* W2  = (const float*)d_in[5];
    const float* b2  = (const float*)d_in[6];

    qsim<<<BATCH, 1024, 0, stream>>>(x, rot, ent, W1, b1, W2, b2,
                                     (float*)d_out, (long long)out_size,
                                     in_sizes[0], in_sizes[1], in_sizes[2],
                                     in_sizes[3], in_sizes[4], in_sizes[5],
                                     in_sizes[6]);
}